// Round 1
// baseline (85.907 us; speedup 1.0000x reference)
//
#include <hip/hip_runtime.h>
#include <math.h>

// Chamfer distance: B=4, N=M=4096, D=3, fp32.
// result = 100 * mean_b( 0.5 * ( mean_m min_n d2 + mean_n min_m d2 ) )
// Decompose d2 = |q|^2 + (|r|^2 - 2 q.r); min over refs of the paren term.
//
// Stage 1: grid (16 query-chunks, 4 batches, 2 dirs * 4 ref-quarters).
//   Each block: 256 threads = 256 query points; loads its 1024-ref quarter
//   into LDS as float4(rx,ry,rz,|r|^2); each thread computes
//   q2 + min_j(r2_j - 2 q.r_j) over the quarter -> pm[q_global*4 + quarter].
// Stage 2: one block, 1024 threads: min over the 4 quarters per query,
//   sum over all 32768 queries, scale, write scalar.

#define NPTS   4096
#define NBATCH 4
#define RSPLIT 4
#define RCHUNK (NPTS / RSPLIT)   // 1024
#define QPB    256
// 100 * (1/B) * 0.5 * (1/NPTS) applied to the grand sum of all mins:
#define SCALE  (50.0f / (float)(NBATCH * NPTS))

__global__ __launch_bounds__(QPB) void chamfer_stage1(
    const float* __restrict__ a1, const float* __restrict__ a2,
    float* __restrict__ pm)
{
    __shared__ float4 refs[RCHUNK];   // 16 KB

    const int b    = blockIdx.y;
    const int dir  = blockIdx.z >> 2;        // 0: q=a1,r=a2 ; 1: q=a2,r=a1
    const int h    = blockIdx.z & 3;         // ref quarter
    const float* q = (dir == 0) ? a1 : a2;
    const float* r = (dir == 0) ? a2 : a1;
    q += (size_t)b * NPTS * 3;
    r += (size_t)b * NPTS * 3;

    // Stage the ref quarter into LDS with |r|^2 precomputed.
    const int base = h * RCHUNK;
    for (int j = threadIdx.x; j < RCHUNK; j += QPB) {
        const int g = base + j;
        float rx = r[3 * g + 0];
        float ry = r[3 * g + 1];
        float rz = r[3 * g + 2];
        float r2 = rx * rx + ry * ry + rz * rz;
        refs[j] = make_float4(rx, ry, rz, r2);
    }
    __syncthreads();

    const int qi = blockIdx.x * QPB + threadIdx.x;
    const float qx = q[3 * qi + 0];
    const float qy = q[3 * qi + 1];
    const float qz = q[3 * qi + 2];
    const float q2  = qx * qx + qy * qy + qz * qz;
    const float qx2 = -2.0f * qx;
    const float qy2 = -2.0f * qy;
    const float qz2 = -2.0f * qz;

    // 4 independent min accumulators to break the dependency chain.
    float m0 = INFINITY, m1 = INFINITY, m2 = INFINITY, m3 = INFINITY;
    #pragma unroll 4
    for (int j = 0; j < RCHUNK; j += 4) {
        float4 p0 = refs[j + 0];
        float4 p1 = refs[j + 1];
        float4 p2 = refs[j + 2];
        float4 p3 = refs[j + 3];
        float t0 = fmaf(qz2, p0.z, fmaf(qy2, p0.y, fmaf(qx2, p0.x, p0.w)));
        float t1 = fmaf(qz2, p1.z, fmaf(qy2, p1.y, fmaf(qx2, p1.x, p1.w)));
        float t2 = fmaf(qz2, p2.z, fmaf(qy2, p2.y, fmaf(qx2, p2.x, p2.w)));
        float t3 = fmaf(qz2, p3.z, fmaf(qy2, p3.y, fmaf(qx2, p3.x, p3.w)));
        m0 = fminf(m0, t0);
        m1 = fminf(m1, t1);
        m2 = fminf(m2, t2);
        m3 = fminf(m3, t3);
    }
    float m = fminf(fminf(m0, m1), fminf(m2, m3)) + q2;

    // global query index across (dir, batch, point)
    const int qg = ((dir * NBATCH + b) * NPTS + qi);
    pm[qg * RSPLIT + h] = m;
}

__global__ __launch_bounds__(1024) void chamfer_stage2(
    const float4* __restrict__ pm, float* __restrict__ out)
{
    __shared__ float wsum[16];
    const int nq = 2 * NBATCH * NPTS;   // 32768 queries
    float s = 0.0f;
    for (int qg = threadIdx.x; qg < nq; qg += 1024) {
        float4 p = pm[qg];
        s += fminf(fminf(p.x, p.y), fminf(p.z, p.w));
    }
    // wave64 reduce
    for (int off = 32; off > 0; off >>= 1) s += __shfl_down(s, off);
    if ((threadIdx.x & 63) == 0) wsum[threadIdx.x >> 6] = s;
    __syncthreads();
    if (threadIdx.x < 64) {
        float v = (threadIdx.x < 16) ? wsum[threadIdx.x] : 0.0f;
        for (int off = 8; off > 0; off >>= 1) v += __shfl_down(v, off);
        if (threadIdx.x == 0) out[0] = v * SCALE;
    }
}

extern "C" void kernel_launch(void* const* d_in, const int* in_sizes, int n_in,
                              void* d_out, int out_size, void* d_ws, size_t ws_size,
                              hipStream_t stream) {
    const float* a1 = (const float*)d_in[0];
    const float* a2 = (const float*)d_in[1];
    float* out = (float*)d_out;
    float* pm  = (float*)d_ws;   // 2*4*4096*4 floats = 512 KB partial mins

    chamfer_stage1<<<dim3(NPTS / QPB, NBATCH, 2 * RSPLIT), QPB, 0, stream>>>(a1, a2, pm);
    chamfer_stage2<<<1, 1024, 0, stream>>>((const float4*)pm, out);
}

// Round 2
// 72.305 us; speedup vs baseline: 1.1881x; 1.1881x over previous
//
#include <hip/hip_runtime.h>
#include <math.h>

// Chamfer distance: B=4, N=M=4096, D=3, fp32.
// result = 100 * mean_b( 0.5 * ( mean_m min_n d2 + mean_n min_m d2 ) )
// d2 = |q|^2 + (|r|^2 - 2 q.r); min over refs of the paren term, add |q|^2.
//
// R1 lesson: one ds_read_b128 per (wave, ref) with 64-lane broadcast is
// LDS-pipe-bound (12 cyc/read regardless of broadcast -> 98k cyc/CU = 41us).
// R2: register-block 8 queries per thread so each LDS read feeds 32 VALU ops
// (VALU-bound, ~7us). pm laid out [chunk][query] so stores+loads coalesce.

#define NPTS     4096
#define NBATCH   4
#define RSPLIT   32                    // ref chunks per direction
#define RCHUNK   (NPTS / RSPLIT)       // 128 refs per chunk
#define QPB      256                   // threads per block
#define QPT      8                     // queries per thread (register-blocked)
#define QBLK     (QPB * QPT)           // 2048 queries per block
#define NQTOT    (2 * NBATCH * NPTS)   // 32768 query slots (both directions)
// 100 * (1/B) * 0.5 * (1/NPTS) applied to the grand sum of all mins:
#define SCALE    (50.0f / (float)(NBATCH * NPTS))

__global__ __launch_bounds__(QPB) void chamfer_stage1(
    const float* __restrict__ a1, const float* __restrict__ a2,
    float* __restrict__ pm)
{
    __shared__ float4 refs[RCHUNK];   // 2 KB

    const int b   = blockIdx.y;
    const int dir = blockIdx.z >> 5;       // 0: q=a1,r=a2 ; 1: q=a2,r=a1
    const int c   = blockIdx.z & 31;       // ref chunk
    const float* q = (dir == 0) ? a1 : a2;
    const float* r = (dir == 0) ? a2 : a1;
    q += (size_t)b * NPTS * 3;
    r += (size_t)b * NPTS * 3;

    // Stage this ref chunk into LDS with |r|^2 precomputed (128 < 256 thr).
    if (threadIdx.x < RCHUNK) {
        const int g = c * RCHUNK + threadIdx.x;
        float rx = r[3 * g + 0];
        float ry = r[3 * g + 1];
        float rz = r[3 * g + 2];
        refs[threadIdx.x] = make_float4(rx, ry, rz, rx * rx + ry * ry + rz * rz);
    }

    // Load 8 queries per thread into registers (stride QPB -> coalesced-ish).
    const int q0 = blockIdx.x * QBLK + threadIdx.x;
    float qx2[QPT], qy2[QPT], qz2[QPT], q2[QPT];
    #pragma unroll
    for (int k = 0; k < QPT; ++k) {
        const int qi = q0 + k * QPB;
        float x = q[3 * qi + 0];
        float y = q[3 * qi + 1];
        float z = q[3 * qi + 2];
        q2[k]  = x * x + y * y + z * z;
        qx2[k] = -2.0f * x;
        qy2[k] = -2.0f * y;
        qz2[k] = -2.0f * z;
    }
    __syncthreads();

    float mins[QPT];
    #pragma unroll
    for (int k = 0; k < QPT; ++k) mins[k] = INFINITY;

    // Each LDS broadcast read feeds 8 independent fma+min chains.
    #pragma unroll 2
    for (int j = 0; j < RCHUNK; ++j) {
        float4 p = refs[j];
        #pragma unroll
        for (int k = 0; k < QPT; ++k) {
            float t = fmaf(qz2[k], p.z,
                      fmaf(qy2[k], p.y,
                      fmaf(qx2[k], p.x, p.w)));
            mins[k] = fminf(mins[k], t);
        }
    }

    // pm[chunk][query_global] -> coalesced store (lanes consecutive in qg).
    const int qgbase = (dir * NBATCH + b) * NPTS + q0;
    #pragma unroll
    for (int k = 0; k < QPT; ++k) {
        pm[(size_t)c * NQTOT + qgbase + k * QPB] = mins[k] + q2[k];
    }
}

// Stage 2: one thread per query; min over the 32 chunk-partials (coalesced),
// then block-wide sum -> psum[block].
__global__ __launch_bounds__(256) void chamfer_stage2(
    const float* __restrict__ pm, float* __restrict__ psum)
{
    const int qg = blockIdx.x * 256 + threadIdx.x;
    float m = INFINITY;
    #pragma unroll
    for (int c = 0; c < RSPLIT; ++c)
        m = fminf(m, pm[(size_t)c * NQTOT + qg]);

    float s = m;
    for (int off = 32; off > 0; off >>= 1) s += __shfl_down(s, off);
    __shared__ float wsum[4];
    if ((threadIdx.x & 63) == 0) wsum[threadIdx.x >> 6] = s;
    __syncthreads();
    if (threadIdx.x == 0)
        psum[blockIdx.x] = wsum[0] + wsum[1] + wsum[2] + wsum[3];
}

// Stage 3: sum the 128 block partials, scale, write the scalar.
__global__ __launch_bounds__(64) void chamfer_stage3(
    const float* __restrict__ psum, float* __restrict__ out)
{
    float s = psum[threadIdx.x] + psum[threadIdx.x + 64];
    for (int off = 32; off > 0; off >>= 1) s += __shfl_down(s, off);
    if (threadIdx.x == 0) out[0] = s * SCALE;
}

extern "C" void kernel_launch(void* const* d_in, const int* in_sizes, int n_in,
                              void* d_out, int out_size, void* d_ws, size_t ws_size,
                              hipStream_t stream) {
    const float* a1 = (const float*)d_in[0];
    const float* a2 = (const float*)d_in[1];
    float* out  = (float*)d_out;
    float* pm   = (float*)d_ws;                           // 32*32768 floats = 4 MB
    float* psum = (float*)((char*)d_ws + (size_t)RSPLIT * NQTOT * sizeof(float));

    chamfer_stage1<<<dim3(NPTS / QBLK, NBATCH, 2 * RSPLIT), QPB, 0, stream>>>(a1, a2, pm);
    chamfer_stage2<<<NQTOT / 256, 256, 0, stream>>>(pm, psum);
    chamfer_stage3<<<1, 64, 0, stream>>>(psum, out);
}

// Round 3
// 71.916 us; speedup vs baseline: 1.1946x; 1.0054x over previous
//
#include <hip/hip_runtime.h>
#include <math.h>

// Chamfer distance: B=4, N=M=4096, D=3, fp32.
// result = 100 * mean_b( 0.5 * ( mean_m min_n d2 + mean_n min_m d2 ) )
// d2 = |q|^2 + (|r|^2 - 2 q.r); min over refs of (|r|^2 - 2 q.r), add |q|^2.
//
// R2 lesson: ~41us of dur is the harness's 268MB d_ws re-poison (structural
// floor). Our 3-kernel + 4MB pm round-trip was ~31us vs ~7us VALU floor.
// R3: one block = 64 queries x ALL 4096 refs (64.5KB LDS, stride-65 float4
// pad -> conflict-free 16-way multicast). QPT=16 halves LDS-pipe traffic vs
// R2. Cross-slice min via shfl_xor in-register; block writes ONE partial
// sum. 2 dispatches, no pm buffer.

#define NPTS     4096
#define NBATCH   4
#define QPB      256                   // threads per block
#define QBLK     64                    // queries per block
#define QPT      16                    // queries per thread
#define NSLICE   64                    // ref slices per block (= QPB/(QBLK/QPT))
#define RSLICE   (NPTS / NSLICE)       // 64 refs per slice
#define SSTRIDE  65                    // float4 stride pad (bank-conflict-free)
#define NBLK     (2 * NBATCH * (NPTS / QBLK))   // 512 blocks
// 100 * (1/B) * 0.5 * (1/NPTS) applied to grand sum of all mins:
#define SCALE    (50.0f / (float)(NBATCH * NPTS))

__global__ __launch_bounds__(QPB, 2) void chamfer_main(
    const float* __restrict__ a1, const float* __restrict__ a2,
    float* __restrict__ psum)
{
    __shared__ float4 refs[NSLICE * SSTRIDE];  // 65 KB
    __shared__ float4 qlds[QBLK];              // 1 KB: (-2x,-2y,-2z,|q|^2)
    __shared__ float  pm2[4][QBLK];            // per-wave partial mins, 1 KB

    const int bid = blockIdx.x;
    const int dir = bid >> 8;              // 0: q=a1,r=a2 ; 1: q=a2,r=a1
    const int b   = (bid >> 6) & 3;
    const int qc  = bid & 63;
    const float* q = (dir == 0) ? a1 : a2;
    const float* r = (dir == 0) ? a2 : a1;
    q += (size_t)b * NPTS * 3 + (size_t)qc * QBLK * 3;
    r += (size_t)b * NPTS * 3;

    const int tid = threadIdx.x;

    // Stage all 4096 refs: slice s at refs[s*65 + j], |r|^2 precomputed.
    // Per wave: 64 consecutive g -> one slice, contiguous j -> standard b128.
    for (int g = tid; g < NPTS; g += QPB) {
        float rx = r[3 * g + 0];
        float ry = r[3 * g + 1];
        float rz = r[3 * g + 2];
        refs[(g >> 6) * SSTRIDE + (g & 63)] =
            make_float4(rx, ry, rz, rx * rx + ry * ry + rz * rz);
    }
    // Stage this block's 64 queries.
    if (tid < QBLK) {
        float x = q[3 * tid + 0];
        float y = q[3 * tid + 1];
        float z = q[3 * tid + 2];
        qlds[tid] = make_float4(-2.0f * x, -2.0f * y, -2.0f * z,
                                x * x + y * y + z * z);
    }
    __syncthreads();

    // Thread t: queries (t&3)*16 + k (k=0..15), ref slice s = t>>2.
    const int qg = (tid & 3) * QPT;
    const int s  = tid >> 2;
    float qx2[QPT], qy2[QPT], qz2[QPT];
    #pragma unroll
    for (int k = 0; k < QPT; ++k) {
        float4 ql = qlds[qg + k];
        qx2[k] = ql.x; qy2[k] = ql.y; qz2[k] = ql.z;
    }

    float mins[QPT];
    #pragma unroll
    for (int k = 0; k < QPT; ++k) mins[k] = INFINITY;

    // Main loop: 1 LDS read feeds 16 independent fma-chains (128 VALU-cyc).
    const float4* rp = &refs[s * SSTRIDE];
    #pragma unroll 2
    for (int j = 0; j < RSLICE; ++j) {
        float4 p = rp[j];
        #pragma unroll
        for (int k = 0; k < QPT; ++k) {
            float t = fmaf(qz2[k], p.z,
                      fmaf(qy2[k], p.y,
                      fmaf(qx2[k], p.x, p.w)));
            mins[k] = fminf(mins[k], t);
        }
    }

    // Cross-slice min within the wave: lanes sharing (t&3) hold the same
    // queries over 16 different slices -> shfl_xor reduce over {4,8,16,32}.
    #pragma unroll
    for (int m = 4; m <= 32; m <<= 1) {
        #pragma unroll
        for (int k = 0; k < QPT; ++k)
            mins[k] = fminf(mins[k], __shfl_xor(mins[k], m));
    }
    const int wv = tid >> 6;
    if ((tid & 63) < 4) {
        #pragma unroll
        for (int k = 0; k < QPT; ++k)
            pm2[wv][qg + k] = mins[k];
    }
    __syncthreads();

    // Threads 0..63: min over 4 waves, add |q|^2, wave-sum -> psum[bid].
    if (tid < QBLK) {
        float m = fminf(fminf(pm2[0][tid], pm2[1][tid]),
                        fminf(pm2[2][tid], pm2[3][tid]));
        float v = m + qlds[tid].w;
        for (int off = 32; off > 0; off >>= 1) v += __shfl_down(v, off);
        if (tid == 0) psum[bid] = v;
    }
}

__global__ __launch_bounds__(256) void chamfer_final(
    const float* __restrict__ psum, float* __restrict__ out)
{
    float s = psum[threadIdx.x] + psum[threadIdx.x + 256];
    for (int off = 32; off > 0; off >>= 1) s += __shfl_down(s, off);
    __shared__ float wsum[4];
    if ((threadIdx.x & 63) == 0) wsum[threadIdx.x >> 6] = s;
    __syncthreads();
    if (threadIdx.x == 0)
        out[0] = (wsum[0] + wsum[1] + wsum[2] + wsum[3]) * SCALE;
}

extern "C" void kernel_launch(void* const* d_in, const int* in_sizes, int n_in,
                              void* d_out, int out_size, void* d_ws, size_t ws_size,
                              hipStream_t stream) {
    const float* a1 = (const float*)d_in[0];
    const float* a2 = (const float*)d_in[1];
    float* out  = (float*)d_out;
    float* psum = (float*)d_ws;    // 512 floats

    chamfer_main<<<NBLK, QPB, 0, stream>>>(a1, a2, psum);
    chamfer_final<<<1, 256, 0, stream>>>(psum, out);
}